// Round 1
// baseline (3285.376 us; speedup 1.0000x reference)
//
#include <hip/hip_runtime.h>
#include <hip/hip_bf16.h>

// Problem constants
#define C      128
#define SP     21952          // 28*28*28
#define PT     87808          // 4*SP
#define LW     343            // 7^3 window length
#define EPS_   1e-6f
#define SCALE_ 0.17677669529663687f  // 32^-0.5

// misc workspace layout (floats)
#define MISC_A   0
#define MISC_B   128
#define MISC_BQK 256
#define MISC_BV  512
#define MISC_SUM 640
#define MISC_SQ  768
#define MISC_A2  896
#define MISC_B2  1024

__device__ __forceinline__ float b2f(unsigned short u){
  return __uint_as_float(((unsigned int)u) << 16);
}
__device__ __forceinline__ unsigned short f2b(float f){
  unsigned int u = __float_as_uint(f);
  u += 0x7fffu + ((u >> 16) & 1u);     // round-to-nearest-even
  return (unsigned short)(u >> 16);
}

// K0: per-channel mean/var of x -> folded scale a=rstd*g, shift b'=b-mean*a
__global__ void k0_stats(const float* __restrict__ x, const float* __restrict__ g,
                         const float* __restrict__ b, float* __restrict__ misc){
  int c = blockIdx.x;
  float s = 0.f, ss = 0.f;
  for (int bb = 0; bb < 4; ++bb){
    const float* p = x + (size_t)(bb*C + c) * SP;
    for (int i = threadIdx.x; i < SP; i += 256){
      float v = p[i]; s += v; ss += v*v;
    }
  }
  __shared__ float rs[256], rq[256];
  rs[threadIdx.x] = s; rq[threadIdx.x] = ss;
  __syncthreads();
  for (int off = 128; off > 0; off >>= 1){
    if (threadIdx.x < off){ rs[threadIdx.x] += rs[threadIdx.x+off]; rq[threadIdx.x] += rq[threadIdx.x+off]; }
    __syncthreads();
  }
  if (threadIdx.x == 0){
    float mean = rs[0] / (float)PT;
    float var  = rq[0] / (float)PT - mean*mean;
    float a = rsqrtf(var + EPS_) * g[c];
    misc[MISC_A + c] = a;
    misc[MISC_B + c] = b[c] - mean * a;
  }
}

// K1: fold BN shift through the 1x1 weights: bias_o = sum_c W[o,c]*bvec[c]
__global__ void k1_bias(const float* __restrict__ wqk, const float* __restrict__ wvv,
                        float* __restrict__ misc){
  int o = blockIdx.x*128 + threadIdx.x;   // grid 3 x 128 = 384
  const float* bv = misc + MISC_B;
  float acc = 0.f;
  if (o < 256){
    const float* wr = wqk + (size_t)o*128;
    for (int c = 0; c < 128; ++c) acc += wr[c]*bv[c];
    misc[MISC_BQK + o] = acc;
  } else {
    const float* wr = wvv + (size_t)(o-256)*128;
    for (int c = 0; c < 128; ++c) acc += wr[c]*bv[c];
    misc[MISC_BV + (o-256)] = acc;
  }
}

// K2: qkv projection GEMM. Output q,k,v bf16 in window layout [bw][h][l][32].
// Strided ("grid") windows: spatial h = s1*4+w1 etc. Each thread -> 8 consecutive
// dd of one (pair,head) => one 16B store per tensor.
__global__ __launch_bounds__(256) void k2_qkv(const float* __restrict__ x,
        const float* __restrict__ wqk, const float* __restrict__ wvv,
        const float* __restrict__ misc,
        unsigned short* __restrict__ qg, unsigned short* __restrict__ kg,
        unsigned short* __restrict__ vg){
  __shared__ __align__(16) float xs[128*64];
  __shared__ __align__(16) float wsh[32*128];
  int t = threadIdx.x;
  int P0 = blockIdx.x * 64;
  int obase = blockIdx.y * 32;
  int b = P0 / SP;
  int sp0 = P0 % SP;
  const float* xb = x + (size_t)b*C*SP + sp0;
  for (int idx = t; idx < 8192; idx += 256){
    int c = idx >> 6, p = idx & 63;
    xs[idx] = xb[(size_t)c*SP + p] * misc[MISC_A + c];
  }
  for (int idx = t; idx < 4096; idx += 256){
    int orow = idx >> 7, cc = idx & 127;
    int og = obase + orow;
    wsh[idx] = (og < 256) ? wqk[(size_t)og*128 + cc] : wvv[(size_t)(og-256)*128 + cc];
  }
  __syncthreads();
  int p  = t & 63;
  int o0 = (t >> 6) * 8;
  float acc[8];
  #pragma unroll
  for (int j = 0; j < 8; ++j){
    int o = obase + o0 + j;
    acc[j] = (o < 256) ? misc[MISC_BQK + o] : misc[MISC_BV + (o - 256)];
  }
  const float4* w4p = reinterpret_cast<const float4*>(wsh);
  for (int cq = 0; cq < 32; ++cq){
    float x0 = xs[(cq*4+0)*64 + p];
    float x1 = xs[(cq*4+1)*64 + p];
    float x2 = xs[(cq*4+2)*64 + p];
    float x3 = xs[(cq*4+3)*64 + p];
    #pragma unroll
    for (int j = 0; j < 8; ++j){
      float4 wf = w4p[(o0+j)*32 + cq];
      acc[j] += wf.x*x0 + wf.y*x1 + wf.z*x2 + wf.w*x3;
    }
  }
  int sp = sp0 + p;
  int h_ = sp / 784, rem = sp % 784;
  int w_ = rem / 28, d_ = rem % 28;
  int w1 = h_ & 3, s1 = h_ >> 2;
  int w2 = w_ & 3, s2 = w_ >> 2;
  int w3 = d_ & 3, s3 = d_ >> 2;
  int bw = ((b*4 + w1)*4 + w2)*4 + w3;
  int l  = (s1*7 + s2)*7 + s3;
  int oglob = obase + o0;
  bool isv = (oglob >= 256);
  unsigned int pk[4];
  #pragma unroll
  for (int jj = 0; jj < 4; ++jj){
    float lo = acc[2*jj], hi = acc[2*jj+1];
    if (isv){ lo = fmaxf(lo, 0.f); hi = fmaxf(hi, 0.f); }   // relu on v only
    pk[jj] = (unsigned int)f2b(lo) | ((unsigned int)f2b(hi) << 16);
  }
  int hh = (oglob >> 5) & 3;
  int dd0 = oglob & 31;
  unsigned short* dst = (oglob < 128) ? qg : (oglob < 256 ? kg : vg);
  size_t oidx = (((size_t)bw*4 + hh)*LW + l)*32 + dd0;
  *reinterpret_cast<uint4*>(dst + oidx) = make_uint4(pk[0], pk[1], pk[2], pk[3]);
}

// K3: attention per (window, head). k,v staged bf16 in LDS (58KB). Block-synchronous
// steps of 8 rows: score+softmax (waves over m) -> barrier -> PV (threads over row,d).
__global__ __launch_bounds__(256) void k3_attn(const unsigned short* __restrict__ qg,
        const unsigned short* __restrict__ kg, const unsigned short* __restrict__ vg,
        unsigned short* __restrict__ xatt){
  __shared__ __align__(16) unsigned short klds[343*36];   // [m][dd], pad 36
  __shared__ __align__(16) unsigned short vlds[32*348];   // [d][m], pad 348
  __shared__ __align__(16) float plds[8*344];             // normalized probs
  int bh = blockIdx.x;
  int bw = bh >> 2, h = bh & 3;
  int t = threadIdx.x;
  const unsigned short* kbase = kg + (size_t)bh*LW*32;
  const unsigned short* vbase = vg + (size_t)bh*LW*32;
  const unsigned short* qbase = qg + (size_t)bh*LW*32;
  const ushort4* k4g = reinterpret_cast<const ushort4*>(kbase);
  for (int qi = t; qi < LW*8; qi += 256){
    int m = qi >> 3, dq = qi & 7;
    ushort4 kk = k4g[qi];
    *reinterpret_cast<ushort4*>(&klds[m*36 + dq*4]) = kk;
  }
  for (int idx = t; idx < LW*32; idx += 256){
    int l = idx >> 5, d = idx & 31;
    vlds[d*348 + l] = vbase[idx];
  }
  for (int idx = t; idx < 32*5; idx += 256){
    int d = idx / 5, l = 343 + idx % 5;
    vlds[d*348 + l] = 0;                      // zero tail so vec reads see 0*0
  }
  __syncthreads();
  int wid = t >> 6, lane = t & 63;
  int rsd = t >> 5, dd = t & 31;
  int w1 = (bw>>4)&3, w2 = (bw>>2)&3, w3 = bw&3, b = bw>>6;
  for (int step = 0; step < 43; ++step){
    int r0 = step*8 + wid*2;
    int r1 = r0 + 1;
    bool v1 = r1 < 343;
    if (r0 < 343){
      int rr1 = v1 ? r1 : r0;
      float qa0[32], qa1[32];
      const uint4* q16 = reinterpret_cast<const uint4*>(qbase);
      #pragma unroll
      for (int i = 0; i < 4; ++i){
        uint4 a = q16[r0*4 + i];
        uint4 c = q16[rr1*4 + i];
        qa0[i*8+0]=__uint_as_float(a.x<<16); qa0[i*8+1]=__uint_as_float(a.x&0xffff0000u);
        qa0[i*8+2]=__uint_as_float(a.y<<16); qa0[i*8+3]=__uint_as_float(a.y&0xffff0000u);
        qa0[i*8+4]=__uint_as_float(a.z<<16); qa0[i*8+5]=__uint_as_float(a.z&0xffff0000u);
        qa0[i*8+6]=__uint_as_float(a.w<<16); qa0[i*8+7]=__uint_as_float(a.w&0xffff0000u);
        qa1[i*8+0]=__uint_as_float(c.x<<16); qa1[i*8+1]=__uint_as_float(c.x&0xffff0000u);
        qa1[i*8+2]=__uint_as_float(c.y<<16); qa1[i*8+3]=__uint_as_float(c.y&0xffff0000u);
        qa1[i*8+4]=__uint_as_float(c.z<<16); qa1[i*8+5]=__uint_as_float(c.z&0xffff0000u);
        qa1[i*8+6]=__uint_as_float(c.w<<16); qa1[i*8+7]=__uint_as_float(c.w&0xffff0000u);
      }
      float s0[6], s1[6];
      #pragma unroll
      for (int j = 0; j < 6; ++j){
        int m = lane + j*64;
        float a0 = 0.f, a1 = 0.f;
        if (m < 343){
          const ushort4* krow = reinterpret_cast<const ushort4*>(&klds[m*36]);
          #pragma unroll
          for (int dq = 0; dq < 8; ++dq){
            ushort4 kk = krow[dq];
            float k0 = b2f(kk.x), k1 = b2f(kk.y), k2 = b2f(kk.z), k3 = b2f(kk.w);
            a0 += qa0[dq*4+0]*k0 + qa0[dq*4+1]*k1 + qa0[dq*4+2]*k2 + qa0[dq*4+3]*k3;
            a1 += qa1[dq*4+0]*k0 + qa1[dq*4+1]*k1 + qa1[dq*4+2]*k2 + qa1[dq*4+3]*k3;
          }
        }
        s0[j] = a0; s1[j] = a1;
      }
      float mx0 = -1e30f, mx1 = -1e30f;
      #pragma unroll
      for (int j = 0; j < 6; ++j){
        if (lane + j*64 < 343){ mx0 = fmaxf(mx0, s0[j]); mx1 = fmaxf(mx1, s1[j]); }
      }
      #pragma unroll
      for (int off = 32; off > 0; off >>= 1){
        mx0 = fmaxf(mx0, __shfl_xor(mx0, off));
        mx1 = fmaxf(mx1, __shfl_xor(mx1, off));
      }
      float e0[6], e1[6], sum0 = 0.f, sum1 = 0.f;
      #pragma unroll
      for (int j = 0; j < 6; ++j){
        bool ok = (lane + j*64) < 343;
        e0[j] = ok ? __expf((s0[j]-mx0)*SCALE_) : 0.f;
        e1[j] = ok ? __expf((s1[j]-mx1)*SCALE_) : 0.f;
        sum0 += e0[j]; sum1 += e1[j];
      }
      #pragma unroll
      for (int off = 32; off > 0; off >>= 1){
        sum0 += __shfl_xor(sum0, off);
        sum1 += __shfl_xor(sum1, off);
      }
      float is0 = 1.f/sum0, is1 = 1.f/sum1;
      #pragma unroll
      for (int j = 0; j < 6; ++j){
        int m = lane + j*64;
        if (m < 343){
          plds[(wid*2+0)*344 + m] = e0[j]*is0;
          if (v1) plds[(wid*2+1)*344 + m] = e1[j]*is1;
        }
      }
      if (lane == 0){ plds[(wid*2+0)*344 + 343] = 0.f; plds[(wid*2+1)*344 + 343] = 0.f; }
    }
    __syncthreads();
    int row = step*8 + rsd;
    if (row < 343){
      float acc = 0.f;
      const float4* prow   = reinterpret_cast<const float4*>(&plds[rsd*344]);
      const ushort4* vrow  = reinterpret_cast<const ushort4*>(&vlds[dd*348]);
      #pragma unroll 4
      for (int mq = 0; mq < 86; ++mq){
        float4 pv = prow[mq];
        ushort4 vv = vrow[mq];
        acc += pv.x*b2f(vv.x) + pv.y*b2f(vv.y) + pv.z*b2f(vv.z) + pv.w*b2f(vv.w);
      }
      int ss1 = row/49, ss2 = (row/7)%7, ss3 = row%7;
      int sp = (ss1*4+w1)*784 + (ss2*4+w2)*28 + (ss3*4+w3);
      xatt[((size_t)b*SP + sp)*128 + h*32 + dd] = f2b(acc);
    }
    __syncthreads();
  }
}

// K4: 3x3x3 conv, channels-last bf16 in/out, fp32 accumulate. 32oc x 4^3 pos per
// block, 8-ic LDS chunks, register-blocked rows (2 adjacent y-rows per thread).
__global__ __launch_bounds__(256) void k4_conv(const unsigned short* __restrict__ xag,
        const float* __restrict__ wcl, unsigned short* __restrict__ yg){
  __shared__ float xls[8*216];       // [i][6*6*6]
  __shared__ float wls[32*217];      // [oc][i*27+tap], pad 217
  int t = threadIdx.x;
  int stile = blockIdx.x;
  int ocb = blockIdx.y * 32;
  int b = stile / 343;
  int srem = stile % 343;
  int z0 = (srem / 49) * 4, y0 = ((srem / 7) % 7) * 4, x0 = (srem % 7) * 4;
  int ocr = t & 31;
  int qp  = t >> 5;                 // 0..7 -> quads 2qp, 2qp+1
  int qz  = qp >> 1;
  int qy0 = (qp << 1) & 3;          // 0 or 2
  float acc[8] = {0,0,0,0,0,0,0,0};
  for (int ic0 = 0; ic0 < 128; ic0 += 8){
    for (int idx = t; idx < 1728; idx += 256){
      int i = idx & 7, pos = idx >> 3;
      int uz = pos / 36, uy = (pos / 6) % 6, ux = pos % 6;
      int zz = z0 - 1 + uz, yy = y0 - 1 + uy, xx = x0 - 1 + ux;
      float v = 0.f;
      if (zz >= 0 && zz < 28 && yy >= 0 && yy < 28 && xx >= 0 && xx < 28)
        v = b2f(xag[(((size_t)b*SP) + zz*784 + yy*28 + xx)*128 + ic0 + i]);
      xls[i*216 + pos] = v;
    }
    for (int idx = t; idx < 6912; idx += 256){
      int orr = idx / 216, rem2 = idx % 216;   // rem2 = i*27+tap, i<8
      wls[orr*217 + rem2] = wcl[((size_t)(ocb+orr)*128 + ic0)*27 + rem2];
    }
    __syncthreads();
    for (int i = 0; i < 8; ++i){
      const float* xi = &xls[i*216];
      #pragma unroll
      for (int dz = 0; dz < 3; ++dz){
        #pragma unroll
        for (int dy = 0; dy < 3; ++dy){
          const float* xr = xi + (qz+dz)*36 + (qy0+dy)*6;
          float a0=xr[0],a1=xr[1],a2=xr[2],a3=xr[3],a4=xr[4],a5=xr[5];
          float a6=xr[6],a7=xr[7],a8=xr[8],a9=xr[9],a10=xr[10],a11=xr[11];
          const float* wp = &wls[ocr*217 + i*27 + dz*9 + dy*3];
          float w0=wp[0], w1=wp[1], w2=wp[2];
          acc[0] += w0*a0 + w1*a1 + w2*a2;
          acc[1] += w0*a1 + w1*a2 + w2*a3;
          acc[2] += w0*a2 + w1*a3 + w2*a4;
          acc[3] += w0*a3 + w1*a4 + w2*a5;
          acc[4] += w0*a6 + w1*a7 + w2*a8;
          acc[5] += w0*a7 + w1*a8 + w2*a9;
          acc[6] += w0*a8 + w1*a9 + w2*a10;
          acc[7] += w0*a9 + w1*a10 + w2*a11;
        }
      }
    }
    __syncthreads();
  }
  #pragma unroll
  for (int q = 0; q < 2; ++q){
    #pragma unroll
    for (int px = 0; px < 4; ++px){
      size_t sp = (size_t)(z0+qz)*784 + (size_t)(y0+qy0+q)*28 + (x0+px);
      yg[((size_t)b*SP + sp)*128 + ocb + ocr] = f2b(acc[q*4+px]);
    }
  }
}

// K5: per-channel sum/sumsq of y via lane-private channel partials + atomics
__global__ void k5_ystats(const unsigned short* __restrict__ yg, float* __restrict__ misc){
  int t = threadIdx.x;
  float s = 0.f, ss = 0.f;
  size_t base = (size_t)blockIdx.x * 32768 + t;
  for (int k = 0; k < 128; ++k){
    float v = b2f(yg[base + (size_t)k*256]);
    s += v; ss += v*v;
  }
  __shared__ float rs[256], rq[256];
  rs[t] = s; rq[t] = ss;
  __syncthreads();
  if (t < 128){
    atomicAdd(&misc[MISC_SUM + t], rs[t] + rs[t+128]);
    atomicAdd(&misc[MISC_SQ  + t], rq[t] + rq[t+128]);
  }
}

__global__ void k5b_finstats(const float* __restrict__ gcl, const float* __restrict__ bcl,
                             float* __restrict__ misc){
  int c = threadIdx.x;
  float mean = misc[MISC_SUM+c] / (float)PT;
  float var  = misc[MISC_SQ +c] / (float)PT - mean*mean;
  float a = gcl[c] * rsqrtf(var + EPS_);
  misc[MISC_A2+c] = a;
  misc[MISC_B2+c] = bcl[c] - mean*a;
}

// K6: out = shortcut + Wproj @ (x_att + silu(bn(y)))
__global__ __launch_bounds__(256) void k6_final(const unsigned short* __restrict__ xag,
        const unsigned short* __restrict__ yg, const float* __restrict__ wproj,
        const float* __restrict__ xin, const float* __restrict__ misc,
        float* __restrict__ out){
  __shared__ __align__(16) float tls[128*65];   // [c][p] pad 65
  __shared__ __align__(16) float wls[32*128];
  int t = threadIdx.x;
  int P0 = blockIdx.x * 64;
  int b = P0 / SP, sp0 = P0 % SP;
  for (int idx = t; idx < 8192; idx += 256){
    int c = idx & 127, p = idx >> 7;
    size_t g = (size_t)(P0 + p)*128 + c;
    float yv = b2f(yg[g]) * misc[MISC_A2+c] + misc[MISC_B2+c];
    float sil = yv / (1.f + __expf(-yv));
    tls[c*65 + p] = b2f(xag[g]) + sil;
  }
  int p = t & 63, og = t >> 6;
  for (int qtr = 0; qtr < 4; ++qtr){
    __syncthreads();
    for (int idx = t; idx < 4096; idx += 256)
      wls[idx] = wproj[qtr*4096 + idx];
    __syncthreads();
    float acc[8];
    #pragma unroll
    for (int j = 0; j < 8; ++j) acc[j] = 0.f;
    const float4* w4p = reinterpret_cast<const float4*>(wls);
    for (int cq = 0; cq < 32; ++cq){
      float x0 = tls[(cq*4+0)*65 + p];
      float x1 = tls[(cq*4+1)*65 + p];
      float x2 = tls[(cq*4+2)*65 + p];
      float x3 = tls[(cq*4+3)*65 + p];
      #pragma unroll
      for (int j = 0; j < 8; ++j){
        float4 wf = w4p[(og*8+j)*32 + cq];
        acc[j] += wf.x*x0 + wf.y*x1 + wf.z*x2 + wf.w*x3;
      }
    }
    #pragma unroll
    for (int j = 0; j < 8; ++j){
      int o = qtr*32 + og*8 + j;
      size_t gaddr = ((size_t)b*128 + o)*SP + sp0 + p;
      out[gaddr] = xin[gaddr] + acc[j];
    }
  }
}

extern "C" void kernel_launch(void* const* d_in, const int* in_sizes, int n_in,
                              void* d_out, int out_size, void* d_ws, size_t ws_size,
                              hipStream_t stream){
  const float* x      = (const float*)d_in[0];
  const float* g_in   = (const float*)d_in[1];
  const float* b_in   = (const float*)d_in[2];
  const float* w_qk   = (const float*)d_in[3];
  const float* w_v    = (const float*)d_in[4];
  const float* w_cl   = (const float*)d_in[5];
  const float* g_cl   = (const float*)d_in[6];
  const float* b_cl   = (const float*)d_in[7];
  const float* w_proj = (const float*)d_in[8];
  float* out = (float*)d_out;

  // workspace: q,k,v,x_att,y as bf16 (22.48 MB each), misc floats at the end.
  char* ws = (char*)d_ws;
  unsigned short* qg  = (unsigned short*)ws;
  unsigned short* kg  = qg  + 11239424;
  unsigned short* vg  = kg  + 11239424;
  unsigned short* xag = vg  + 11239424;
  unsigned short* yg  = xag + 11239424;
  float* misc = (float*)(ws + (size_t)5*22478848);   // 112,394,240 B offset

  hipMemsetAsync(misc + MISC_SUM, 0, 256*sizeof(float), stream);
  k0_stats   <<<128, 256, 0, stream>>>(x, g_in, b_in, misc);
  k1_bias    <<<3, 128, 0, stream>>>(w_qk, w_v, misc);
  k2_qkv     <<<dim3(1372,12), 256, 0, stream>>>(x, w_qk, w_v, misc, qg, kg, vg);
  k3_attn    <<<1024, 256, 0, stream>>>(qg, kg, vg, xag);
  k4_conv    <<<dim3(1372,4), 256, 0, stream>>>(xag, w_cl, yg);
  k5_ystats  <<<343, 256, 0, stream>>>(yg, misc);
  k5b_finstats<<<1, 128, 0, stream>>>(g_cl, b_cl, misc);
  k6_final   <<<1372, 256, 0, stream>>>(xag, yg, w_proj, x, misc, out);
}

// Round 2
// 1399.378 us; speedup vs baseline: 2.3477x; 2.3477x over previous
//
#include <hip/hip_runtime.h>
#include <hip/hip_bf16.h>

// Problem constants
#define C      128
#define SP     21952          // 28*28*28
#define PT     87808          // 4*SP
#define LW     343            // 7^3 window length
#define EPS_   1e-6f
#define SCALE_ 0.17677669529663687f  // 32^-0.5

// misc workspace layout (floats)
#define MISC_A   0
#define MISC_B   128
#define MISC_BQK 256
#define MISC_BV  512
#define MISC_SUM 640
#define MISC_SQ  768
#define MISC_A2  896
#define MISC_B2  1024

typedef __attribute__((ext_vector_type(8))) short bf16x8;
typedef __attribute__((ext_vector_type(4))) float f32x4;

__device__ __forceinline__ float b2f(unsigned short u){
  return __uint_as_float(((unsigned int)u) << 16);
}
__device__ __forceinline__ unsigned short f2b(float f){
  unsigned int u = __float_as_uint(f);
  u += 0x7fffu + ((u >> 16) & 1u);     // round-to-nearest-even
  return (unsigned short)(u >> 16);
}

// K0: per-channel mean/var of x -> folded scale a=rstd*g, shift b'=b-mean*a
__global__ void k0_stats(const float* __restrict__ x, const float* __restrict__ g,
                         const float* __restrict__ b, float* __restrict__ misc){
  int c = blockIdx.x;
  float s = 0.f, ss = 0.f;
  for (int bb = 0; bb < 4; ++bb){
    const float* p = x + (size_t)(bb*C + c) * SP;
    for (int i = threadIdx.x; i < SP; i += 256){
      float v = p[i]; s += v; ss += v*v;
    }
  }
  __shared__ float rs[256], rq[256];
  rs[threadIdx.x] = s; rq[threadIdx.x] = ss;
  __syncthreads();
  for (int off = 128; off > 0; off >>= 1){
    if (threadIdx.x < off){ rs[threadIdx.x] += rs[threadIdx.x+off]; rq[threadIdx.x] += rq[threadIdx.x+off]; }
    __syncthreads();
  }
  if (threadIdx.x == 0){
    float mean = rs[0] / (float)PT;
    float var  = rq[0] / (float)PT - mean*mean;
    float a = rsqrtf(var + EPS_) * g[c];
    misc[MISC_A + c] = a;
    misc[MISC_B + c] = b[c] - mean * a;
  }
}

// K1: fold BN shift through the 1x1 weights: bias_o = sum_c W[o,c]*bvec[c]
__global__ void k1_bias(const float* __restrict__ wqk, const float* __restrict__ wvv,
                        float* __restrict__ misc){
  int o = blockIdx.x*128 + threadIdx.x;   // grid 3 x 128 = 384
  const float* bv = misc + MISC_B;
  float acc = 0.f;
  if (o < 256){
    const float* wr = wqk + (size_t)o*128;
    for (int c = 0; c < 128; ++c) acc += wr[c]*bv[c];
    misc[MISC_BQK + o] = acc;
  } else {
    const float* wr = wvv + (size_t)(o-256)*128;
    for (int c = 0; c < 128; ++c) acc += wr[c]*bv[c];
    misc[MISC_BV + (o-256)] = acc;
  }
}

// K2: qkv projection GEMM. Output q,k,v bf16 in window layout [bw][h][l][32].
__global__ __launch_bounds__(256) void k2_qkv(const float* __restrict__ x,
        const float* __restrict__ wqk, const float* __restrict__ wvv,
        const float* __restrict__ misc,
        unsigned short* __restrict__ qg, unsigned short* __restrict__ kg,
        unsigned short* __restrict__ vg){
  __shared__ __align__(16) float xs[128*64];
  __shared__ __align__(16) float wsh[32*128];
  int t = threadIdx.x;
  int P0 = blockIdx.x * 64;
  int obase = blockIdx.y * 32;
  int b = P0 / SP;
  int sp0 = P0 % SP;
  const float* xb = x + (size_t)b*C*SP + sp0;
  for (int idx = t; idx < 8192; idx += 256){
    int c = idx >> 6, p = idx & 63;
    xs[idx] = xb[(size_t)c*SP + p] * misc[MISC_A + c];
  }
  for (int idx = t; idx < 4096; idx += 256){
    int orow = idx >> 7, cc = idx & 127;
    int og = obase + orow;
    wsh[idx] = (og < 256) ? wqk[(size_t)og*128 + cc] : wvv[(size_t)(og-256)*128 + cc];
  }
  __syncthreads();
  int p  = t & 63;
  int o0 = (t >> 6) * 8;
  float acc[8];
  #pragma unroll
  for (int j = 0; j < 8; ++j){
    int o = obase + o0 + j;
    acc[j] = (o < 256) ? misc[MISC_BQK + o] : misc[MISC_BV + (o - 256)];
  }
  const float4* w4p = reinterpret_cast<const float4*>(wsh);
  for (int cq = 0; cq < 32; ++cq){
    float x0 = xs[(cq*4+0)*64 + p];
    float x1 = xs[(cq*4+1)*64 + p];
    float x2 = xs[(cq*4+2)*64 + p];
    float x3 = xs[(cq*4+3)*64 + p];
    #pragma unroll
    for (int j = 0; j < 8; ++j){
      float4 wf = w4p[(o0+j)*32 + cq];
      acc[j] += wf.x*x0 + wf.y*x1 + wf.z*x2 + wf.w*x3;
    }
  }
  int sp = sp0 + p;
  int h_ = sp / 784, rem = sp % 784;
  int w_ = rem / 28, d_ = rem % 28;
  int w1 = h_ & 3, s1 = h_ >> 2;
  int w2 = w_ & 3, s2 = w_ >> 2;
  int w3 = d_ & 3, s3 = d_ >> 2;
  int bw = ((b*4 + w1)*4 + w2)*4 + w3;
  int l  = (s1*7 + s2)*7 + s3;
  int oglob = obase + o0;
  bool isv = (oglob >= 256);
  unsigned int pk[4];
  #pragma unroll
  for (int jj = 0; jj < 4; ++jj){
    float lo = acc[2*jj], hi = acc[2*jj+1];
    if (isv){ lo = fmaxf(lo, 0.f); hi = fmaxf(hi, 0.f); }   // relu on v only
    pk[jj] = (unsigned int)f2b(lo) | ((unsigned int)f2b(hi) << 16);
  }
  int hh = (oglob >> 5) & 3;
  int dd0 = oglob & 31;
  unsigned short* dst = (oglob < 128) ? qg : (oglob < 256 ? kg : vg);
  size_t oidx = (((size_t)bw*4 + hh)*LW + l)*32 + dd0;
  *reinterpret_cast<uint4*>(dst + oidx) = make_uint4(pk[0], pk[1], pk[2], pk[3]);
}

// K3: attention per (window, head). k,v staged bf16 in LDS (58KB).
__global__ __launch_bounds__(256) void k3_attn(const unsigned short* __restrict__ qg,
        const unsigned short* __restrict__ kg, const unsigned short* __restrict__ vg,
        unsigned short* __restrict__ xatt){
  __shared__ __align__(16) unsigned short klds[343*36];   // [m][dd], pad 36
  __shared__ __align__(16) unsigned short vlds[32*348];   // [d][m], pad 348
  __shared__ __align__(16) float plds[8*344];             // normalized probs
  int bh = blockIdx.x;
  int bw = bh >> 2, h = bh & 3;
  int t = threadIdx.x;
  const unsigned short* kbase = kg + (size_t)bh*LW*32;
  const unsigned short* vbase = vg + (size_t)bh*LW*32;
  const unsigned short* qbase = qg + (size_t)bh*LW*32;
  const ushort4* k4g = reinterpret_cast<const ushort4*>(kbase);
  for (int qi = t; qi < LW*8; qi += 256){
    int m = qi >> 3, dq = qi & 7;
    ushort4 kk = k4g[qi];
    *reinterpret_cast<ushort4*>(&klds[m*36 + dq*4]) = kk;
  }
  for (int idx = t; idx < LW*32; idx += 256){
    int l = idx >> 5, d = idx & 31;
    vlds[d*348 + l] = vbase[idx];
  }
  for (int idx = t; idx < 32*5; idx += 256){
    int d = idx / 5, l = 343 + idx % 5;
    vlds[d*348 + l] = 0;
  }
  __syncthreads();
  int wid = t >> 6, lane = t & 63;
  int rsd = t >> 5, dd = t & 31;
  int w1 = (bw>>4)&3, w2 = (bw>>2)&3, w3 = bw&3, b = bw>>6;
  for (int step = 0; step < 43; ++step){
    int r0 = step*8 + wid*2;
    int r1 = r0 + 1;
    bool v1 = r1 < 343;
    if (r0 < 343){
      int rr1 = v1 ? r1 : r0;
      float qa0[32], qa1[32];
      const uint4* q16 = reinterpret_cast<const uint4*>(qbase);
      #pragma unroll
      for (int i = 0; i < 4; ++i){
        uint4 a = q16[r0*4 + i];
        uint4 c = q16[rr1*4 + i];
        qa0[i*8+0]=__uint_as_float(a.x<<16); qa0[i*8+1]=__uint_as_float(a.x&0xffff0000u);
        qa0[i*8+2]=__uint_as_float(a.y<<16); qa0[i*8+3]=__uint_as_float(a.y&0xffff0000u);
        qa0[i*8+4]=__uint_as_float(a.z<<16); qa0[i*8+5]=__uint_as_float(a.z&0xffff0000u);
        qa0[i*8+6]=__uint_as_float(a.w<<16); qa0[i*8+7]=__uint_as_float(a.w&0xffff0000u);
        qa1[i*8+0]=__uint_as_float(c.x<<16); qa1[i*8+1]=__uint_as_float(c.x&0xffff0000u);
        qa1[i*8+2]=__uint_as_float(c.y<<16); qa1[i*8+3]=__uint_as_float(c.y&0xffff0000u);
        qa1[i*8+4]=__uint_as_float(c.z<<16); qa1[i*8+5]=__uint_as_float(c.z&0xffff0000u);
        qa1[i*8+6]=__uint_as_float(c.w<<16); qa1[i*8+7]=__uint_as_float(c.w&0xffff0000u);
      }
      float s0[6], s1[6];
      #pragma unroll
      for (int j = 0; j < 6; ++j){
        int m = lane + j*64;
        float a0 = 0.f, a1 = 0.f;
        if (m < 343){
          const ushort4* krow = reinterpret_cast<const ushort4*>(&klds[m*36]);
          #pragma unroll
          for (int dq = 0; dq < 8; ++dq){
            ushort4 kk = krow[dq];
            float k0 = b2f(kk.x), k1 = b2f(kk.y), k2 = b2f(kk.z), k3 = b2f(kk.w);
            a0 += qa0[dq*4+0]*k0 + qa0[dq*4+1]*k1 + qa0[dq*4+2]*k2 + qa0[dq*4+3]*k3;
            a1 += qa1[dq*4+0]*k0 + qa1[dq*4+1]*k1 + qa1[dq*4+2]*k2 + qa1[dq*4+3]*k3;
          }
        }
        s0[j] = a0; s1[j] = a1;
      }
      float mx0 = -1e30f, mx1 = -1e30f;
      #pragma unroll
      for (int j = 0; j < 6; ++j){
        if (lane + j*64 < 343){ mx0 = fmaxf(mx0, s0[j]); mx1 = fmaxf(mx1, s1[j]); }
      }
      #pragma unroll
      for (int off = 32; off > 0; off >>= 1){
        mx0 = fmaxf(mx0, __shfl_xor(mx0, off));
        mx1 = fmaxf(mx1, __shfl_xor(mx1, off));
      }
      float e0[6], e1[6], sum0 = 0.f, sum1 = 0.f;
      #pragma unroll
      for (int j = 0; j < 6; ++j){
        bool ok = (lane + j*64) < 343;
        e0[j] = ok ? __expf((s0[j]-mx0)*SCALE_) : 0.f;
        e1[j] = ok ? __expf((s1[j]-mx1)*SCALE_) : 0.f;
        sum0 += e0[j]; sum1 += e1[j];
      }
      #pragma unroll
      for (int off = 32; off > 0; off >>= 1){
        sum0 += __shfl_xor(sum0, off);
        sum1 += __shfl_xor(sum1, off);
      }
      float is0 = 1.f/sum0, is1 = 1.f/sum1;
      #pragma unroll
      for (int j = 0; j < 6; ++j){
        int m = lane + j*64;
        if (m < 343){
          plds[(wid*2+0)*344 + m] = e0[j]*is0;
          if (v1) plds[(wid*2+1)*344 + m] = e1[j]*is1;
        }
      }
      if (lane == 0){ plds[(wid*2+0)*344 + 343] = 0.f; plds[(wid*2+1)*344 + 343] = 0.f; }
    }
    __syncthreads();
    int row = step*8 + rsd;
    if (row < 343){
      float acc = 0.f;
      const float4* prow   = reinterpret_cast<const float4*>(&plds[rsd*344]);
      const ushort4* vrow  = reinterpret_cast<const ushort4*>(&vlds[dd*348]);
      #pragma unroll 4
      for (int mq = 0; mq < 86; ++mq){
        float4 pv = prow[mq];
        ushort4 vv = vrow[mq];
        acc += pv.x*b2f(vv.x) + pv.y*b2f(vv.y) + pv.z*b2f(vv.z) + pv.w*b2f(vv.w);
      }
      int ss1 = row/49, ss2 = (row/7)%7, ss3 = row%7;
      int sp = (ss1*4+w1)*784 + (ss2*4+w2)*28 + (ss3*4+w3);
      xatt[((size_t)b*SP + sp)*128 + h*32 + dd] = f2b(acc);
    }
    __syncthreads();
  }
}

// K_wprep: w_cl [oc][ic][27] fp32 -> wbf bf16 slices [h][tap][kg][oc][8]
// slice s = h*27+tap is a contiguous 16384B tile matching global_load_lds lane order.
__global__ void k_wprep(const float* __restrict__ wcl, unsigned short* __restrict__ wbf){
  int f = blockIdx.x*256 + threadIdx.x;      // 442368 total
  int j  = f & 7;
  int oc = (f >> 3) & 127;
  int kgr= (f >> 10) & 7;
  int sl = f >> 13;                          // 0..53
  int h  = sl / 27, tap = sl % 27;
  int ic = h*64 + kgr*8 + j;
  wbf[f] = f2b(wcl[((size_t)oc*128 + ic)*27 + tap]);
}

// K4: 3x3x3 conv as implicit GEMM on mfma_f32_16x16x32_bf16.
// Block: 64 positions (4x4x4 tile) x 128 oc. 4 waves: wave = (mhalf, ohalf),
// each wave 2 m-tiles x 4 n-tiles. K = 27 taps x 128 ic (2 ic-halves of 64).
// A: 6^3 halo in LDS [kg][pos][8ic]; B: per-(half,tap) 16KB weight tile,
// double-buffered via global_load_lds(16B).
__global__ __launch_bounds__(256) void k4_mfma(const unsigned short* __restrict__ xag,
        const unsigned short* __restrict__ wbf, unsigned short* __restrict__ yg){
  __shared__ __align__(16) unsigned short halo[8*216*8];   // 27648 B
  __shared__ __align__(16) unsigned short wt[2][8192];     // 2 x 16384 B
  int t = threadIdx.x, wid = t >> 6, lane = t & 63;
  int stile = blockIdx.x;
  int b = stile / 343, srem = stile % 343;
  int z0 = (srem/49)*4, y0 = ((srem/7)%7)*4, x0 = (srem%7)*4;
  int mhalf = wid & 1, ohalf = wid >> 1;
  int nn = lane & 15, quad = lane >> 4;
  int mA = mhalf*32 + nn;          // m-tile 0 row of this lane
  int mB = mA + 16;                // m-tile 1 row
  int hp0 = (mA>>4)*36 + ((mA>>2)&3)*6 + (mA&3);
  int hp1 = (mB>>4)*36 + ((mB>>2)&3)*6 + (mB&3);
  f32x4 acc[2][4] = {};

  // issue weight loads for slice s into wt[buf]: 4 x (64 lanes x 16B)
  #define WLOAD(s_, buf_) do { \
    const unsigned short* gs = wbf + (size_t)(s_)*8192 + (size_t)(wid*4*64 + lane)*8; \
    _Pragma("unroll") \
    for (int it = 0; it < 4; ++it){ \
      __builtin_amdgcn_global_load_lds( \
        (const __attribute__((address_space(1))) unsigned int*)(gs + it*512), \
        (__attribute__((address_space(3))) unsigned int*)(&wt[buf_][(wid*4+it)*512]), \
        16, 0, 0); \
    } \
  } while(0)

  int s = 0;
  WLOAD(0, 0);
  for (int h = 0; h < 2; ++h){
    // stage halo for this ic-half: layout [kg][pos][8], 1728 16B-chunks
    for (int cidx = t; cidx < 1728; cidx += 256){
      int kgr = cidx / 216, pos = cidx % 216;
      int uz = pos / 36, r36 = pos % 36, uy = r36 / 6, ux = r36 % 6;
      int zz = z0 - 1 + uz, yy = y0 - 1 + uy, xx = x0 - 1 + ux;
      uint4 v = make_uint4(0u,0u,0u,0u);
      if (zz >= 0 && zz < 28 && yy >= 0 && yy < 28 && xx >= 0 && xx < 28)
        v = *reinterpret_cast<const uint4*>(
              &xag[(((size_t)b*SP) + zz*784 + yy*28 + xx)*128 + h*64 + kgr*8]);
      *reinterpret_cast<uint4*>(&halo[(size_t)cidx*8]) = v;
    }
    __syncthreads();   // halo ready; pending WLOAD drained
    for (int tap = 0; tap < 27; ++tap){
      if (s + 1 < 54) WLOAD(s + 1, (s + 1) & 1);
      const unsigned short* wc = wt[s & 1];
      int dz = tap / 9, r9 = tap % 9, dy = r9 / 3, dx = r9 % 3;
      int off = dz*36 + dy*6 + dx;
      #pragma unroll
      for (int ks = 0; ks < 2; ++ks){
        int ksel = ks*4 + quad;
        bf16x8 a0 = *reinterpret_cast<const bf16x8*>(&halo[(ksel*216 + hp0 + off)*8]);
        bf16x8 a1 = *reinterpret_cast<const bf16x8*>(&halo[(ksel*216 + hp1 + off)*8]);
        #pragma unroll
        for (int nt = 0; nt < 4; ++nt){
          bf16x8 bb = *reinterpret_cast<const bf16x8*>(&wc[(ksel*128 + ohalf*64 + nt*16 + nn)*8]);
          acc[0][nt] = __builtin_amdgcn_mfma_f32_16x16x32_bf16(a0, bb, acc[0][nt], 0, 0, 0);
          acc[1][nt] = __builtin_amdgcn_mfma_f32_16x16x32_bf16(a1, bb, acc[1][nt], 0, 0, 0);
        }
      }
      ++s;
      __syncthreads();  // everyone done with wt[s-1&1]; next WLOAD drained next iter
    }
  }
  // epilogue: C/D col=lane&15 -> oc, row=quad*4+reg -> m
  #pragma unroll
  for (int mt = 0; mt < 2; ++mt){
    #pragma unroll
    for (int nt = 0; nt < 4; ++nt){
      #pragma unroll
      for (int r = 0; r < 4; ++r){
        int m = mhalf*32 + mt*16 + quad*4 + r;
        int oc = ohalf*64 + nt*16 + nn;
        int pos = (z0 + (m>>4))*784 + (y0 + ((m>>2)&3))*28 + (x0 + (m&3));
        yg[((size_t)b*SP + pos)*128 + oc] = f2b(acc[mt][nt][r]);
      }
    }
  }
  #undef WLOAD
}

// K5: per-channel sum/sumsq of y via lane-private channel partials + atomics
__global__ void k5_ystats(const unsigned short* __restrict__ yg, float* __restrict__ misc){
  int t = threadIdx.x;
  float s = 0.f, ss = 0.f;
  size_t base = (size_t)blockIdx.x * 32768 + t;
  for (int k = 0; k < 128; ++k){
    float v = b2f(yg[base + (size_t)k*256]);
    s += v; ss += v*v;
  }
  __shared__ float rs[256], rq[256];
  rs[t] = s; rq[t] = ss;
  __syncthreads();
  if (t < 128){
    atomicAdd(&misc[MISC_SUM + t], rs[t] + rs[t+128]);
    atomicAdd(&misc[MISC_SQ  + t], rq[t] + rq[t+128]);
  }
}

__global__ void k5b_finstats(const float* __restrict__ gcl, const float* __restrict__ bcl,
                             float* __restrict__ misc){
  int c = threadIdx.x;
  float mean = misc[MISC_SUM+c] / (float)PT;
  float var  = misc[MISC_SQ +c] / (float)PT - mean*mean;
  float a = gcl[c] * rsqrtf(var + EPS_);
  misc[MISC_A2+c] = a;
  misc[MISC_B2+c] = bcl[c] - mean*a;
}

// K6: out = shortcut + Wproj @ (x_att + silu(bn(y)))
__global__ __launch_bounds__(256) void k6_final(const unsigned short* __restrict__ xag,
        const unsigned short* __restrict__ yg, const float* __restrict__ wproj,
        const float* __restrict__ xin, const float* __restrict__ misc,
        float* __restrict__ out){
  __shared__ __align__(16) float tls[128*65];   // [c][p] pad 65
  __shared__ __align__(16) float wls[32*128];
  int t = threadIdx.x;
  int P0 = blockIdx.x * 64;
  int b = P0 / SP, sp0 = P0 % SP;
  for (int idx = t; idx < 8192; idx += 256){
    int c = idx & 127, p = idx >> 7;
    size_t g = (size_t)(P0 + p)*128 + c;
    float yv = b2f(yg[g]) * misc[MISC_A2+c] + misc[MISC_B2+c];
    float sil = yv / (1.f + __expf(-yv));
    tls[c*65 + p] = b2f(xag[g]) + sil;
  }
  int p = t & 63, og = t >> 6;
  for (int qtr = 0; qtr < 4; ++qtr){
    __syncthreads();
    for (int idx = t; idx < 4096; idx += 256)
      wls[idx] = wproj[qtr*4096 + idx];
    __syncthreads();
    float acc[8];
    #pragma unroll
    for (int j = 0; j < 8; ++j) acc[j] = 0.f;
    const float4* w4p = reinterpret_cast<const float4*>(wls);
    for (int cq = 0; cq < 32; ++cq){
      float x0 = tls[(cq*4+0)*65 + p];
      float x1 = tls[(cq*4+1)*65 + p];
      float x2 = tls[(cq*4+2)*65 + p];
      float x3 = tls[(cq*4+3)*65 + p];
      #pragma unroll
      for (int j = 0; j < 8; ++j){
        float4 wf = w4p[(og*8+j)*32 + cq];
        acc[j] += wf.x*x0 + wf.y*x1 + wf.z*x2 + wf.w*x3;
      }
    }
    #pragma unroll
    for (int j = 0; j < 8; ++j){
      int o = qtr*32 + og*8 + j;
      size_t gaddr = ((size_t)b*128 + o)*SP + sp0 + p;
      out[gaddr] = xin[gaddr] + acc[j];
    }
  }
}

extern "C" void kernel_launch(void* const* d_in, const int* in_sizes, int n_in,
                              void* d_out, int out_size, void* d_ws, size_t ws_size,
                              hipStream_t stream){
  const float* x      = (const float*)d_in[0];
  const float* g_in   = (const float*)d_in[1];
  const float* b_in   = (const float*)d_in[2];
  const float* w_qk   = (const float*)d_in[3];
  const float* w_v    = (const float*)d_in[4];
  const float* w_cl   = (const float*)d_in[5];
  const float* g_cl   = (const float*)d_in[6];
  const float* b_cl   = (const float*)d_in[7];
  const float* w_proj = (const float*)d_in[8];
  float* out = (float*)d_out;

  // workspace: q,k,v,x_att,y as bf16 (22.48 MB each), misc floats at the end.
  char* ws = (char*)d_ws;
  unsigned short* qg  = (unsigned short*)ws;
  unsigned short* kgp = qg  + 11239424;
  unsigned short* vg  = kgp + 11239424;
  unsigned short* xag = vg  + 11239424;
  unsigned short* yg  = xag + 11239424;
  float* misc = (float*)(ws + (size_t)5*22478848);   // 112,394,240 B offset
  // wbf (884,736 B) reuses the qg region — written AFTER k3 consumed q.
  unsigned short* wbf = qg;

  hipMemsetAsync(misc + MISC_SUM, 0, 256*sizeof(float), stream);
  k0_stats    <<<128, 256, 0, stream>>>(x, g_in, b_in, misc);
  k1_bias     <<<3, 128, 0, stream>>>(w_qk, w_v, misc);
  k2_qkv      <<<dim3(1372,12), 256, 0, stream>>>(x, w_qk, w_v, misc, qg, kgp, vg);
  k3_attn     <<<1024, 256, 0, stream>>>(qg, kgp, vg, xag);
  k_wprep     <<<1728, 256, 0, stream>>>(w_cl, wbf);
  k4_mfma     <<<1372, 256, 0, stream>>>(xag, wbf, yg);
  k5_ystats   <<<343, 256, 0, stream>>>(yg, misc);
  k5b_finstats<<<1, 128, 0, stream>>>(g_cl, b_cl, misc);
  k6_final    <<<1372, 256, 0, stream>>>(xag, yg, w_proj, x, misc, out);
}

// Round 6
// 1395.405 us; speedup vs baseline: 2.3544x; 1.0028x over previous
//
#include <hip/hip_runtime.h>
#include <hip/hip_bf16.h>

// Problem constants
#define C      128
#define SP     21952          // 28*28*28
#define PT     87808          // 4*SP
#define LW     343            // 7^3 window length
#define EPS_   1e-6f
#define SCALE_ 0.17677669529663687f  // 32^-0.5

// misc workspace layout (floats)
#define MISC_A   0
#define MISC_B   128
#define MISC_BQK 256
#define MISC_BV  512
#define MISC_SUM 640
#define MISC_SQ  768
#define MISC_A2  896
#define MISC_B2  1024

typedef __attribute__((ext_vector_type(8))) short bf16x8;
typedef __attribute__((ext_vector_type(4))) float f32x4;

__device__ __forceinline__ float b2f(unsigned short u){
  return __uint_as_float(((unsigned int)u) << 16);
}
__device__ __forceinline__ unsigned short f2b(float f){
  unsigned int u = __float_as_uint(f);
  u += 0x7fffu + ((u >> 16) & 1u);     // round-to-nearest-even
  return (unsigned short)(u >> 16);
}

// K0: per-channel mean/var of x -> folded scale a=rstd*g, shift b'=b-mean*a
__global__ void k0_stats(const float* __restrict__ x, const float* __restrict__ g,
                         const float* __restrict__ b, float* __restrict__ misc){
  int c = blockIdx.x;
  float s = 0.f, ss = 0.f;
  for (int bb = 0; bb < 4; ++bb){
    const float* p = x + (size_t)(bb*C + c) * SP;
    for (int i = threadIdx.x; i < SP; i += 256){
      float v = p[i]; s += v; ss += v*v;
    }
  }
  __shared__ float rs[256], rq[256];
  rs[threadIdx.x] = s; rq[threadIdx.x] = ss;
  __syncthreads();
  for (int off = 128; off > 0; off >>= 1){
    if (threadIdx.x < off){ rs[threadIdx.x] += rs[threadIdx.x+off]; rq[threadIdx.x] += rq[threadIdx.x+off]; }
    __syncthreads();
  }
  if (threadIdx.x == 0){
    float mean = rs[0] / (float)PT;
    float var  = rq[0] / (float)PT - mean*mean;
    float a = rsqrtf(var + EPS_) * g[c];
    misc[MISC_A + c] = a;
    misc[MISC_B + c] = b[c] - mean * a;
  }
}

// K1: fold BN shift through the 1x1 weights: bias_o = sum_c W[o,c]*bvec[c]
__global__ void k1_bias(const float* __restrict__ wqk, const float* __restrict__ wvv,
                        float* __restrict__ misc){
  int o = blockIdx.x*128 + threadIdx.x;   // grid 3 x 128 = 384
  const float* bv = misc + MISC_B;
  float acc = 0.f;
  if (o < 256){
    const float* wr = wqk + (size_t)o*128;
    for (int c = 0; c < 128; ++c) acc += wr[c]*bv[c];
    misc[MISC_BQK + o] = acc;
  } else {
    const float* wr = wvv + (size_t)(o-256)*128;
    for (int c = 0; c < 128; ++c) acc += wr[c]*bv[c];
    misc[MISC_BV + (o-256)] = acc;
  }
}

// K2: qkv projection GEMM. Output q,k,v bf16 in window layout [bw][h][l][32].
// R6: single-block-per-position-tile; the 12 output groups are serialized in a
// loop (k6's proven qtr-loop pattern), so xs is staged ONCE instead of 12x.
__global__ __launch_bounds__(256) void k2_qkv(const float* __restrict__ x,
        const float* __restrict__ wqk, const float* __restrict__ wvv,
        const float* __restrict__ misc,
        unsigned short* __restrict__ qg, unsigned short* __restrict__ kg,
        unsigned short* __restrict__ vg){
  __shared__ __align__(16) float xs[128*64];
  __shared__ __align__(16) float wsh[32*128];
  int t = threadIdx.x;
  int P0 = blockIdx.x * 64;
  int b = P0 / SP;
  int sp0 = P0 % SP;
  const float* xb = x + (size_t)b*C*SP + sp0;
  for (int idx = t; idx < 8192; idx += 256){
    int c = idx >> 6, p = idx & 63;
    xs[idx] = xb[(size_t)c*SP + p] * misc[MISC_A + c];
  }
  int p  = t & 63;
  int o0 = (t >> 6) * 8;
  // window decomposition (loop-invariant)
  int sp = sp0 + p;
  int h_ = sp / 784, rem = sp % 784;
  int w_ = rem / 28, d_ = rem % 28;
  int w1 = h_ & 3, s1 = h_ >> 2;
  int w2 = w_ & 3, s2 = w_ >> 2;
  int w3 = d_ & 3, s3 = d_ >> 2;
  int bw = ((b*4 + w1)*4 + w2)*4 + w3;
  int l  = (s1*7 + s2)*7 + s3;
  for (int oy = 0; oy < 12; ++oy){
    int obase = oy * 32;
    __syncthreads();   // xs ready (first iter) / prev compute done with wsh
    for (int idx = t; idx < 4096; idx += 256){
      int orow = idx >> 7, cc = idx & 127;
      int og = obase + orow;
      wsh[idx] = (og < 256) ? wqk[(size_t)og*128 + cc] : wvv[(size_t)(og-256)*128 + cc];
    }
    __syncthreads();
    float acc[8];
    #pragma unroll
    for (int j = 0; j < 8; ++j){
      int o = obase + o0 + j;
      acc[j] = (o < 256) ? misc[MISC_BQK + o] : misc[MISC_BV + (o - 256)];
    }
    const float4* w4p = reinterpret_cast<const float4*>(wsh);
    for (int cq = 0; cq < 32; ++cq){
      float x0 = xs[(cq*4+0)*64 + p];
      float x1 = xs[(cq*4+1)*64 + p];
      float x2 = xs[(cq*4+2)*64 + p];
      float x3 = xs[(cq*4+3)*64 + p];
      #pragma unroll
      for (int j = 0; j < 8; ++j){
        float4 wf = w4p[(o0+j)*32 + cq];
        acc[j] += wf.x*x0 + wf.y*x1 + wf.z*x2 + wf.w*x3;
      }
    }
    int oglob = obase + o0;
    bool isv = (oglob >= 256);
    unsigned int pk[4];
    #pragma unroll
    for (int jj = 0; jj < 4; ++jj){
      float lo = acc[2*jj], hi = acc[2*jj+1];
      if (isv){ lo = fmaxf(lo, 0.f); hi = fmaxf(hi, 0.f); }   // relu on v only
      pk[jj] = (unsigned int)f2b(lo) | ((unsigned int)f2b(hi) << 16);
    }
    int hh = (oglob >> 5) & 3;
    int dd0 = oglob & 31;
    unsigned short* dst = (oglob < 128) ? qg : (oglob < 256 ? kg : vg);
    size_t oidx = (((size_t)bw*4 + hh)*LW + l)*32 + dd0;
    *reinterpret_cast<uint4*>(dst + oidx) = make_uint4(pk[0], pk[1], pk[2], pk[3]);
  }
}

// K3: attention per (window, head). k,v staged bf16 in LDS (58KB). Block-synchronous
// steps of 8 rows: score+softmax (waves over m) -> barrier -> PV (threads over row,d).
// (Reverted to the round-2 known-good version; the MFMA rewrite NaN'd for reasons
// not yet isolated — see journal.)
__global__ __launch_bounds__(256) void k3_attn(const unsigned short* __restrict__ qg,
        const unsigned short* __restrict__ kg, const unsigned short* __restrict__ vg,
        unsigned short* __restrict__ xatt){
  __shared__ __align__(16) unsigned short klds[343*36];   // [m][dd], pad 36
  __shared__ __align__(16) unsigned short vlds[32*348];   // [d][m], pad 348
  __shared__ __align__(16) float plds[8*344];             // normalized probs
  int bh = blockIdx.x;
  int bw = bh >> 2, h = bh & 3;
  int t = threadIdx.x;
  const unsigned short* kbase = kg + (size_t)bh*LW*32;
  const unsigned short* vbase = vg + (size_t)bh*LW*32;
  const unsigned short* qbase = qg + (size_t)bh*LW*32;
  const ushort4* k4g = reinterpret_cast<const ushort4*>(kbase);
  for (int qi = t; qi < LW*8; qi += 256){
    int m = qi >> 3, dq = qi & 7;
    ushort4 kk = k4g[qi];
    *reinterpret_cast<ushort4*>(&klds[m*36 + dq*4]) = kk;
  }
  for (int idx = t; idx < LW*32; idx += 256){
    int l = idx >> 5, d = idx & 31;
    vlds[d*348 + l] = vbase[idx];
  }
  for (int idx = t; idx < 32*5; idx += 256){
    int d = idx / 5, l = 343 + idx % 5;
    vlds[d*348 + l] = 0;                      // zero tail so vec reads see 0*0
  }
  __syncthreads();
  int wid = t >> 6, lane = t & 63;
  int rsd = t >> 5, dd = t & 31;
  int w1 = (bw>>4)&3, w2 = (bw>>2)&3, w3 = bw&3, b = bw>>6;
  for (int step = 0; step < 43; ++step){
    int r0 = step*8 + wid*2;
    int r1 = r0 + 1;
    bool v1 = r1 < 343;
    if (r0 < 343){
      int rr1 = v1 ? r1 : r0;
      float qa0[32], qa1[32];
      const uint4* q16 = reinterpret_cast<const uint4*>(qbase);
      #pragma unroll
      for (int i = 0; i < 4; ++i){
        uint4 a = q16[r0*4 + i];
        uint4 c = q16[rr1*4 + i];
        qa0[i*8+0]=__uint_as_float(a.x<<16); qa0[i*8+1]=__uint_as_float(a.x&0xffff0000u);
        qa0[i*8+2]=__uint_as_float(a.y<<16); qa0[i*8+3]=__uint_as_float(a.y&0xffff0000u);
        qa0[i*8+4]=__uint_as_float(a.z<<16); qa0[i*8+5]=__uint_as_float(a.z&0xffff0000u);
        qa0[i*8+6]=__uint_as_float(a.w<<16); qa0[i*8+7]=__uint_as_float(a.w&0xffff0000u);
        qa1[i*8+0]=__uint_as_float(c.x<<16); qa1[i*8+1]=__uint_as_float(c.x&0xffff0000u);
        qa1[i*8+2]=__uint_as_float(c.y<<16); qa1[i*8+3]=__uint_as_float(c.y&0xffff0000u);
        qa1[i*8+4]=__uint_as_float(c.z<<16); qa1[i*8+5]=__uint_as_float(c.z&0xffff0000u);
        qa1[i*8+6]=__uint_as_float(c.w<<16); qa1[i*8+7]=__uint_as_float(c.w&0xffff0000u);
      }
      float s0[6], s1[6];
      #pragma unroll
      for (int j = 0; j < 6; ++j){
        int m = lane + j*64;
        float a0 = 0.f, a1 = 0.f;
        if (m < 343){
          const ushort4* krow = reinterpret_cast<const ushort4*>(&klds[m*36]);
          #pragma unroll
          for (int dq = 0; dq < 8; ++dq){
            ushort4 kk = krow[dq];
            float k0 = b2f(kk.x), k1 = b2f(kk.y), k2 = b2f(kk.z), k3 = b2f(kk.w);
            a0 += qa0[dq*4+0]*k0 + qa0[dq*4+1]*k1 + qa0[dq*4+2]*k2 + qa0[dq*4+3]*k3;
            a1 += qa1[dq*4+0]*k0 + qa1[dq*4+1]*k1 + qa1[dq*4+2]*k2 + qa1[dq*4+3]*k3;
          }
        }
        s0[j] = a0; s1[j] = a1;
      }
      float mx0 = -1e30f, mx1 = -1e30f;
      #pragma unroll
      for (int j = 0; j < 6; ++j){
        if (lane + j*64 < 343){ mx0 = fmaxf(mx0, s0[j]); mx1 = fmaxf(mx1, s1[j]); }
      }
      #pragma unroll
      for (int off = 32; off > 0; off >>= 1){
        mx0 = fmaxf(mx0, __shfl_xor(mx0, off));
        mx1 = fmaxf(mx1, __shfl_xor(mx1, off));
      }
      float e0[6], e1[6], sum0 = 0.f, sum1 = 0.f;
      #pragma unroll
      for (int j = 0; j < 6; ++j){
        bool ok = (lane + j*64) < 343;
        e0[j] = ok ? __expf((s0[j]-mx0)*SCALE_) : 0.f;
        e1[j] = ok ? __expf((s1[j]-mx1)*SCALE_) : 0.f;
        sum0 += e0[j]; sum1 += e1[j];
      }
      #pragma unroll
      for (int off = 32; off > 0; off >>= 1){
        sum0 += __shfl_xor(sum0, off);
        sum1 += __shfl_xor(sum1, off);
      }
      float is0 = 1.f/sum0, is1 = 1.f/sum1;
      #pragma unroll
      for (int j = 0; j < 6; ++j){
        int m = lane + j*64;
        if (m < 343){
          plds[(wid*2+0)*344 + m] = e0[j]*is0;
          if (v1) plds[(wid*2+1)*344 + m] = e1[j]*is1;
        }
      }
      if (lane == 0){ plds[(wid*2+0)*344 + 343] = 0.f; plds[(wid*2+1)*344 + 343] = 0.f; }
    }
    __syncthreads();
    int row = step*8 + rsd;
    if (row < 343){
      float acc = 0.f;
      const float4* prow   = reinterpret_cast<const float4*>(&plds[rsd*344]);
      const ushort4* vrow  = reinterpret_cast<const ushort4*>(&vlds[dd*348]);
      #pragma unroll 4
      for (int mq = 0; mq < 86; ++mq){
        float4 pv = prow[mq];
        ushort4 vv = vrow[mq];
        acc += pv.x*b2f(vv.x) + pv.y*b2f(vv.y) + pv.z*b2f(vv.z) + pv.w*b2f(vv.w);
      }
      int ss1 = row/49, ss2 = (row/7)%7, ss3 = row%7;
      int sp = (ss1*4+w1)*784 + (ss2*4+w2)*28 + (ss3*4+w3);
      xatt[((size_t)b*SP + sp)*128 + h*32 + dd] = f2b(acc);
    }
    __syncthreads();
  }
}

// K_wprep: w_cl [oc][ic][27] fp32 -> wbf bf16 slices [h][tap][kg][oc][8]
__global__ void k_wprep(const float* __restrict__ wcl, unsigned short* __restrict__ wbf){
  int f = blockIdx.x*256 + threadIdx.x;      // 442368 total
  int j  = f & 7;
  int oc = (f >> 3) & 127;
  int kgr= (f >> 10) & 7;
  int sl = f >> 13;                          // 0..53
  int h  = sl / 27, tap = sl % 27;
  int ic = h*64 + kgr*8 + j;
  wbf[f] = f2b(wcl[((size_t)oc*128 + ic)*27 + tap]);
}

// K4: 3x3x3 conv as implicit GEMM on mfma_f32_16x16x32_bf16.
__global__ __launch_bounds__(256) void k4_mfma(const unsigned short* __restrict__ xag,
        const unsigned short* __restrict__ wbf, unsigned short* __restrict__ yg){
  __shared__ __align__(16) unsigned short halo[8*216*8];   // 27648 B
  __shared__ __align__(16) unsigned short wt[2][8192];     // 2 x 16384 B
  int t = threadIdx.x, wid = t >> 6, lane = t & 63;
  int stile = blockIdx.x;
  int b = stile / 343, srem = stile % 343;
  int z0 = (srem/49)*4, y0 = ((srem/7)%7)*4, x0 = (srem%7)*4;
  int mhalf = wid & 1, ohalf = wid >> 1;
  int nn = lane & 15, quad = lane >> 4;
  int mA = mhalf*32 + nn;          // m-tile 0 row of this lane
  int mB = mA + 16;                // m-tile 1 row
  int hp0 = (mA>>4)*36 + ((mA>>2)&3)*6 + (mA&3);
  int hp1 = (mB>>4)*36 + ((mB>>2)&3)*6 + (mB&3);
  f32x4 acc[2][4] = {};

  #define WLOAD(s_, buf_) do { \
    const unsigned short* gs = wbf + (size_t)(s_)*8192 + (size_t)(wid*4*64 + lane)*8; \
    _Pragma("unroll") \
    for (int it = 0; it < 4; ++it){ \
      __builtin_amdgcn_global_load_lds( \
        (const __attribute__((address_space(1))) unsigned int*)(gs + it*512), \
        (__attribute__((address_space(3))) unsigned int*)(&wt[buf_][(wid*4+it)*512]), \
        16, 0, 0); \
    } \
  } while(0)

  int s = 0;
  WLOAD(0, 0);
  for (int h = 0; h < 2; ++h){
    for (int cidx = t; cidx < 1728; cidx += 256){
      int kgr = cidx / 216, pos = cidx % 216;
      int uz = pos / 36, r36 = pos % 36, uy = r36 / 6, ux = r36 % 6;
      int zz = z0 - 1 + uz, yy = y0 - 1 + uy, xx = x0 - 1 + ux;
      uint4 v = make_uint4(0u,0u,0u,0u);
      if (zz >= 0 && zz < 28 && yy >= 0 && yy < 28 && xx >= 0 && xx < 28)
        v = *reinterpret_cast<const uint4*>(
              &xag[(((size_t)b*SP) + zz*784 + yy*28 + xx)*128 + h*64 + kgr*8]);
      *reinterpret_cast<uint4*>(&halo[(size_t)cidx*8]) = v;
    }
    __syncthreads();
    for (int tap = 0; tap < 27; ++tap){
      if (s + 1 < 54) WLOAD(s + 1, (s + 1) & 1);
      const unsigned short* wc = wt[s & 1];
      int dz = tap / 9, r9 = tap % 9, dy = r9 / 3, dx = r9 % 3;
      int off = dz*36 + dy*6 + dx;
      #pragma unroll
      for (int ks = 0; ks < 2; ++ks){
        int ksel = ks*4 + quad;
        bf16x8 a0 = *reinterpret_cast<const bf16x8*>(&halo[(ksel*216 + hp0 + off)*8]);
        bf16x8 a1 = *reinterpret_cast<const bf16x8*>(&halo[(ksel*216 + hp1 + off)*8]);
        #pragma unroll
        for (int nt = 0; nt < 4; ++nt){
          bf16x8 bb = *reinterpret_cast<const bf16x8*>(&wc[(ksel*128 + ohalf*64 + nt*16 + nn)*8]);
          acc[0][nt] = __builtin_amdgcn_mfma_f32_16x16x32_bf16(a0, bb, acc[0][nt], 0, 0, 0);
          acc[1][nt] = __builtin_amdgcn_mfma_f32_16x16x32_bf16(a1, bb, acc[1][nt], 0, 0, 0);
        }
      }
      ++s;
      __syncthreads();
    }
  }
  #pragma unroll
  for (int mt = 0; mt < 2; ++mt){
    #pragma unroll
    for (int nt = 0; nt < 4; ++nt){
      #pragma unroll
      for (int r = 0; r < 4; ++r){
        int m = mhalf*32 + mt*16 + quad*4 + r;
        int oc = ohalf*64 + nt*16 + nn;
        int pos = (z0 + (m>>4))*784 + (y0 + ((m>>2)&3))*28 + (x0 + (m&3));
        yg[((size_t)b*SP + pos)*128 + oc] = f2b(acc[mt][nt][r]);
      }
    }
  }
  #undef WLOAD
}

// K5: per-channel sum/sumsq of y via lane-private channel partials + atomics
__global__ void k5_ystats(const unsigned short* __restrict__ yg, float* __restrict__ misc){
  int t = threadIdx.x;
  float s = 0.f, ss = 0.f;
  size_t base = (size_t)blockIdx.x * 32768 + t;
  for (int k = 0; k < 128; ++k){
    float v = b2f(yg[base + (size_t)k*256]);
    s += v; ss += v*v;
  }
  __shared__ float rs[256], rq[256];
  rs[t] = s; rq[t] = ss;
  __syncthreads();
  if (t < 128){
    atomicAdd(&misc[MISC_SUM + t], rs[t] + rs[t+128]);
    atomicAdd(&misc[MISC_SQ  + t], rq[t] + rq[t+128]);
  }
}

__global__ void k5b_finstats(const float* __restrict__ gcl, const float* __restrict__ bcl,
                             float* __restrict__ misc){
  int c = threadIdx.x;
  float mean = misc[MISC_SUM+c] / (float)PT;
  float var  = misc[MISC_SQ +c] / (float)PT - mean*mean;
  float a = gcl[c] * rsqrtf(var + EPS_);
  misc[MISC_A2+c] = a;
  misc[MISC_B2+c] = bcl[c] - mean*a;
}

// K6: out = shortcut + Wproj @ (x_att + silu(bn(y)))
__global__ __launch_bounds__(256) void k6_final(const unsigned short* __restrict__ xag,
        const unsigned short* __restrict__ yg, const float* __restrict__ wproj,
        const float* __restrict__ xin, const float* __restrict__ misc,
        float* __restrict__ out){
  __shared__ __align__(16) float tls[128*65];   // [c][p] pad 65
  __shared__ __align__(16) float wls[32*128];
  int t = threadIdx.x;
  int P0 = blockIdx.x * 64;
  int b = P0 / SP, sp0 = P0 % SP;
  for (int idx = t; idx < 8192; idx += 256){
    int c = idx & 127, p = idx >> 7;
    size_t g = (size_t)(P0 + p)*128 + c;
    float yv = b2f(yg[g]) * misc[MISC_A2+c] + misc[MISC_B2+c];
    float sil = yv / (1.f + __expf(-yv));
    tls[c*65 + p] = b2f(xag[g]) + sil;
  }
  int p = t & 63, og = t >> 6;
  for (int qtr = 0; qtr < 4; ++qtr){
    __syncthreads();
    for (int idx = t; idx < 4096; idx += 256)
      wls[idx] = wproj[qtr*4096 + idx];
    __syncthreads();
    float acc[8];
    #pragma unroll
    for (int j = 0; j < 8; ++j) acc[j] = 0.f;
    const float4* w4p = reinterpret_cast<const float4*>(wls);
    for (int cq = 0; cq < 32; ++cq){
      float x0 = tls[(cq*4+0)*65 + p];
      float x1 = tls[(cq*4+1)*65 + p];
      float x2 = tls[(cq*4+2)*65 + p];
      float x3 = tls[(cq*4+3)*65 + p];
      #pragma unroll
      for (int j = 0; j < 8; ++j){
        float4 wf = w4p[(og*8+j)*32 + cq];
        acc[j] += wf.x*x0 + wf.y*x1 + wf.z*x2 + wf.w*x3;
      }
    }
    #pragma unroll
    for (int j = 0; j < 8; ++j){
      int o = qtr*32 + og*8 + j;
      size_t gaddr = ((size_t)b*128 + o)*SP + sp0 + p;
      out[gaddr] = xin[gaddr] + acc[j];
    }
  }
}

extern "C" void kernel_launch(void* const* d_in, const int* in_sizes, int n_in,
                              void* d_out, int out_size, void* d_ws, size_t ws_size,
                              hipStream_t stream){
  const float* x      = (const float*)d_in[0];
  const float* g_in   = (const float*)d_in[1];
  const float* b_in   = (const float*)d_in[2];
  const float* w_qk   = (const float*)d_in[3];
  const float* w_v    = (const float*)d_in[4];
  const float* w_cl   = (const float*)d_in[5];
  const float* g_cl   = (const float*)d_in[6];
  const float* b_cl   = (const float*)d_in[7];
  const float* w_proj = (const float*)d_in[8];
  float* out = (float*)d_out;

  char* ws = (char*)d_ws;
  unsigned short* qg  = (unsigned short*)ws;
  unsigned short* kgp = qg  + 11239424;
  unsigned short* vg  = kgp + 11239424;
  unsigned short* xag = vg  + 11239424;
  unsigned short* yg  = xag + 11239424;
  float* misc = (float*)(ws + (size_t)5*22478848);   // 112,394,240 B offset
  unsigned short* wbf = qg;   // reuses qg region AFTER k3 consumed q

  hipMemsetAsync(misc + MISC_SUM, 0, 256*sizeof(float), stream);
  k0_stats    <<<128, 256, 0, stream>>>(x, g_in, b_in, misc);
  k1_bias     <<<3, 128, 0, stream>>>(w_qk, w_v, misc);
  k2_qkv      <<<1372, 256, 0, stream>>>(x, w_qk, w_v, misc, qg, kgp, vg);
  k3_attn     <<<1024, 256, 0, stream>>>(qg, kgp, vg, xag);
  k_wprep     <<<1728, 256, 0, stream>>>(w_cl, wbf);
  k4_mfma     <<<1372, 256, 0, stream>>>(xag, wbf, yg);
  k5_ystats   <<<343, 256, 0, stream>>>(yg, misc);
  k5b_finstats<<<1, 128, 0, stream>>>(g_cl, b_cl, misc);
  k6_final    <<<1372, 256, 0, stream>>>(xag, yg, w_proj, x, misc, out);
}